// Round 19
// baseline (270.150 us; speedup 1.0000x reference)
//
#include <hip/hip_runtime.h>

#define N_EDGES 1048576
#define N_GRAPH 512
#define MAXE    2304
#define CHUNK   2048
#define SBLK    (N_EDGES / CHUNK)   // 512

typedef __attribute__((ext_vector_type(4))) float floatx4;
typedef __attribute__((ext_vector_type(4))) int intx4;

// ---------------- preprocessing: fully local counting sort ----------------
__global__ void scatter_kernel(const int* __restrict__ src, const int* __restrict__ dst,
                               unsigned* __restrict__ cstab, unsigned short* __restrict__ ebuf) {
    __shared__ unsigned short sbuf[CHUNK];
    __shared__ unsigned short sg[CHUNK];
    __shared__ unsigned lhist[512];
    __shared__ unsigned lscan[512];
    const int t = threadIdx.x;
    const int b = blockIdx.x;
    lhist[t] = 0; lhist[t + 256] = 0;
    __syncthreads();
    const intx4* s4 = (const intx4*)(src + b * CHUNK) + t * 2;
    const intx4* d4 = (const intx4*)(dst + b * CHUNK) + t * 2;
    unsigned short gg[8], pk[8], rr[8];
#pragma unroll
    for (int h = 0; h < 2; ++h) {
        intx4 sv = s4[h], dv = d4[h];
        int ss[4] = {sv.x, sv.y, sv.z, sv.w};
        int dd[4] = {dv.x, dv.y, dv.z, dv.w};
#pragma unroll
        for (int j = 0; j < 4; ++j) {
            unsigned g = ((unsigned)dd[j]) >> 7;
            gg[h * 4 + j] = (unsigned short)g;
            pk[h * 4 + j] = (unsigned short)((ss[j] & 127) | ((dd[j] & 127) << 8));
            rr[h * 4 + j] = (unsigned short)atomicAdd(&lhist[g], 1u);
        }
    }
    __syncthreads();
    unsigned a0 = lhist[t], a1 = lhist[t + 256];
    lscan[t] = a0; lscan[t + 256] = a1;
    __syncthreads();
    for (int d = 1; d < 512; d <<= 1) {
        unsigned v0 = (t >= d) ? lscan[t - d] : 0u;
        unsigned v1 = (t + 256 >= d) ? lscan[t + 256 - d] : 0u;
        __syncthreads();
        lscan[t] += v0; lscan[t + 256] += v1;
        __syncthreads();
    }
    lscan[t] -= a0; lscan[t + 256] -= a1;
    cstab[(size_t)t * SBLK + b]         = (a0 << 16) | lscan[t];
    cstab[(size_t)(t + 256) * SBLK + b] = (a1 << 16) | lscan[t + 256];
    __syncthreads();
#pragma unroll
    for (int j = 0; j < 8; ++j) {
        unsigned pos = lscan[gg[j]] + rr[j];
        sbuf[pos] = pk[j]; sg[pos] = gg[j];
    }
    __syncthreads();
    for (int i = t; i < CHUNK; i += 256)
        ebuf[(size_t)b * CHUNK + i] = sbuf[i];
    (void)sg;
}

// ---------------- GCN layer, 512 threads (in-place X, split csr/coef) -----
template<int CIN, int COUT>
__device__ void gcn_layer(const float* Xin, float* Xio,
                          const float* __restrict__ W, const float* __restrict__ Bv,
                          const float* __restrict__ dinv, const int* __restrict__ offs,
                          const unsigned char* __restrict__ csr,
                          const float* __restrict__ coef, int tid)
{
    constexpr int CL  = COUT / 4;
    constexpr int GR  = 512 / CL;
    constexpr int NPT = 128 / GR;        // 8 / 4 / 2
    const int grp = tid / CL, cl = tid % CL;

    float acc[NPT][4];
#pragma unroll
    for (int ni = 0; ni < NPT; ++ni)
#pragma unroll
        for (int j = 0; j < 4; ++j) acc[ni][j] = 0.f;

#pragma unroll 1                      // keep k-loop rolled: caps wv/xv live ranges
    for (int k = 0; k < CIN; k += 4) {
        float wv[4][4];
#pragma unroll
        for (int i = 0; i < 4; ++i)
            *(floatx4*)wv[i] = *(const floatx4*)(W + (k + i) * COUT + cl * 4);
#pragma unroll
        for (int ni = 0; ni < NPT; ++ni) {
            floatx4 xv = *(const floatx4*)(Xin + (grp * NPT + ni) * CIN + k);
#pragma unroll
            for (int i = 0; i < 4; ++i)
#pragma unroll
                for (int j = 0; j < 4; ++j)
                    acc[ni][j] += xv[i] * wv[i][j];
        }
    }
    __syncthreads();                 // ALL Xin reads done (in-place safe)
#pragma unroll
    for (int ni = 0; ni < NPT; ++ni) {
        floatx4 v; v[0] = acc[ni][0]; v[1] = acc[ni][1]; v[2] = acc[ni][2]; v[3] = acc[ni][3];
        *(floatx4*)(Xio + (grp * NPT + ni) * COUT + cl * 4) = v;
    }
    __syncthreads();                 // H visible

    floatx4 bv = *(const floatx4*)(Bv + cl * 4);
#pragma unroll
    for (int ni = 0; ni < NPT; ++ni) {
        int n = grp * NPT + ni;
        float a[4] = {0.f, 0.f, 0.f, 0.f};
        int o0 = offs[n], o1 = offs[n + 1];
        int p = o0;
        for (; p + 1 < o1; p += 2) {          // 2 independent chains
            int s0 = csr[p], s1 = csr[p + 1];
            float c0 = coef[p], c1 = coef[p + 1];
            floatx4 h0 = *(const floatx4*)(Xio + s0 * COUT + cl * 4);
            floatx4 h1 = *(const floatx4*)(Xio + s1 * COUT + cl * 4);
#pragma unroll
            for (int j = 0; j < 4; ++j) a[j] += h0[j] * c0 + h1[j] * c1;
        }
        if (p < o1) {
            int s = csr[p];
            float cf = coef[p];
            floatx4 h = *(const floatx4*)(Xio + s * COUT + cl * 4);
#pragma unroll
            for (int j = 0; j < 4; ++j) a[j] += h[j] * cf;
        }
        float dn = dinv[n], dnn = dn * dn;
#pragma unroll
        for (int j = 0; j < 4; ++j)
            acc[ni][j] = tanhf(a[j] + acc[ni][j] * dnn + bv[j]);   // reuse acc
    }
    __syncthreads();                 // all H reads done before overwrite
#pragma unroll
    for (int ni = 0; ni < NPT; ++ni) {
        floatx4 v; v[0] = acc[ni][0]; v[1] = acc[ni][1]; v[2] = acc[ni][2]; v[3] = acc[ni][3];
        *(floatx4*)(Xio + (grp * NPT + ni) * COUT + cl * 4) = v;
    }
    __syncthreads();
}

// ---------------- Y accumulation, 512 threads, 4 registers/thread --------
template<int LEN, int OFF>
__device__ void yacc(const float* __restrict__ Xl, const float* __restrict__ W5,
                     int tid, float* __restrict__ Y)
{
    const int w = tid >> 6, lane = tid & 63, c = lane & 15, seg = lane >> 4;
    const float* wr = W5 + c * 256 + OFF + seg * 4;
#pragma unroll
    for (int half = 0; half < 2; ++half) {
        const float* xr = Xl + (w * 16 + half * 8) * LEN + seg * 4;
        float part[8];
#pragma unroll
        for (int r = 0; r < 8; ++r) part[r] = 0.f;
#pragma unroll 2                      // cap in-flight xv loads (spill control)
        for (int t = 0; t < LEN / 16; ++t) {
            floatx4 wv = *(const floatx4*)(wr + 16 * t);
#pragma unroll
            for (int r = 0; r < 8; ++r) {
                floatx4 xv = *(const floatx4*)(xr + r * LEN + 16 * t);
                part[r] += xv[0] * wv[0] + xv[1] * wv[1] + xv[2] * wv[2] + xv[3] * wv[3];
            }
        }
#pragma unroll
        for (int r = 0; r < 8; ++r) {
            float s = part[r];
            s += __shfl_xor(s, 16, 64);
            s += __shfl_xor(s, 32, 64);
            int rg = half * 8 + r;
            if (seg == (rg & 3)) Y[rg >> 2] += s;
        }
    }
}

// ---------------- fused per-graph kernel: 512 threads (R14/R18 config) ----
// bounds(512,4): HW co-schedules two 8-wave blocks per CU (best measured
// regime). This round removes the spill sources (ev[] array, over-unrolled
// matmul/yacc loops) while keeping that occupancy configuration.
__global__ __launch_bounds__(512, 4) void mega_kernel(
    const float* __restrict__ x,
    const float* __restrict__ W1, const float* __restrict__ b1,
    const float* __restrict__ W2, const float* __restrict__ b2,
    const float* __restrict__ W3, const float* __restrict__ b3,
    const float* __restrict__ W4, const float* __restrict__ b4,
    const float* __restrict__ W5, const float* __restrict__ b5,
    const float* __restrict__ W6, const float* __restrict__ b6,
    const float* __restrict__ Wf1, const float* __restrict__ bf1,
    const float* __restrict__ Wf2, const float* __restrict__ bf2,
    const unsigned* __restrict__ cstab, const unsigned short* __restrict__ ebuf,
    float* __restrict__ out)
{
    __shared__ __align__(16) char pool[79248];
    int*   offs = (int*)(pool + 0);                       // int[129]
    float* dinv = (float*)(pool + 520);                   // f32[128]
    float* key  = (float*)(pool + 1032);                  // f32[128]
    unsigned short* ord = (unsigned short*)(pool + 1544); // u16[64]
    int*   ldeg = (int*)(pool + 1672);                    // int[128]
    unsigned char* csr = (unsigned char*)(pool + 2184);   // u8[2304]
    float* coef = (float*)(pool + 4488);                  // f32[2304]
    float* X    = (float*)(pool + 13712);                 // f32[16384] = 64 KB
    // tail overlays inside X (X dead after key + Y handoff):
    float* Yl   = X;                  // 128x16 = 2048 f
    float* ZMP  = X + 2048;           // 16x32  = 512 f
    float* W6s  = X + 3072;           // 2560 f
    float* Z896 = X + 5632;           // 896 f
    float* PART = X + 6528;           // 4x128 = 512 f
    float* FC1  = X + 7552;           // 128 f
    float* LG   = X + 7680;           // 17 f

    const int g   = blockIdx.x;
    const int tid = threadIdx.x;

    // ---- this thread's (block-bucket) run: streamed from global twice ----
    unsigned cs = cstab[(size_t)g * SBLK + tid];
    int start = (int)(cs & 0xFFFFu);
    int myc = (int)(cs >> 16);
    if (myc > 64) myc = 64;                 // safety bound only
    const unsigned short* run = ebuf + (size_t)tid * CHUNK + start;

    // ---- stage x into X EARLY: global loads complete under CSR phase ----
    const float* xg = x + (size_t)g * 16384;
    for (int idx = tid; idx < 4096; idx += 512)
        *(floatx4*)(X + idx * 4) = *(const floatx4*)(xg + idx * 4);

    // ---- degree histogram (pass 1 over run) ----
    if (tid < 128) ldeg[tid] = 0;
    __syncthreads();
    for (int w = 0; w < myc; ++w)
        atomicAdd(&ldeg[(run[w] >> 8) & 127], 1);
    __syncthreads();
    // ---- single-wave shfl scan over 128 degree counts ----
    if (tid < 64) {
        int v0 = ldeg[2 * tid], v1 = ldeg[2 * tid + 1];
        int s = v0 + v1;
        for (int d = 1; d < 64; d <<= 1) {
            int u = __shfl_up(s, d, 64);
            if (tid >= d) s += u;
        }
        int e1 = s - v1, e2 = s;
        offs[2 * tid + 1] = (e1 < MAXE) ? e1 : MAXE;
        offs[2 * tid + 2] = (e2 < MAXE) ? e2 : MAXE;
        if (tid == 0) offs[0] = 0;
    }
    if (tid >= 128 && tid < 256) {
        int n = tid - 128;
        dinv[n] = 1.0f / sqrtf((float)(1 + ldeg[n]));
    }
    __syncthreads();
    if (tid < 128) ldeg[tid] = offs[tid];               // cursor
    __syncthreads();
    // ---- scatter into csr (u8) + coef (f32) (pass 2 over run, L2-hot) ----
    for (int w = 0; w < myc; ++w) {
        unsigned e = run[w];
        int dn_ = (e >> 8) & 127, sn = e & 127;
        int p = atomicAdd(&ldeg[dn_], 1);
        if (p < MAXE) {
            csr[p]  = (unsigned char)sn;
            coef[p] = dinv[sn] * dinv[dn_];
        }
    }
    __syncthreads();   // covers CSR scatter AND the early x staging

    // ---- 4 GCN layers, all in-place in X, + register-Y accumulation ----
    float Y[4] = {0.f, 0.f, 0.f, 0.f};
    gcn_layer<128, 128>(X, X, W1, b1, dinv, offs, csr, coef, tid);
    yacc<128,   0>(X, W5, tid, Y);
    gcn_layer<128,  64>(X, X, W2, b2, dinv, offs, csr, coef, tid);
    yacc< 64, 128>(X, W5, tid, Y);
    gcn_layer< 64,  32>(X, X, W3, b3, dinv, offs, csr, coef, tid);
    yacc< 32, 192>(X, W5, tid, Y);
    gcn_layer< 32,  32>(X, X, W4, b4, dinv, offs, csr, coef, tid);
    yacc< 32, 224>(X, W5, tid, Y);

    // ---- key extraction (before X reuse), then Y -> LDS ----
    if (tid < 128) key[tid] = X[tid * 32 + 31];
    __syncthreads();
    {
        const int w = tid >> 6, lane = tid & 63, c = lane & 15, seg = lane >> 4;
#pragma unroll
        for (int q = 0; q < 4; ++q)
            Yl[(w * 16 + seg + 4 * q) * 16 + c] = Y[q];
    }
    if (tid < 64) ord[tid] = (unsigned short)tid;       // safety default
    for (int idx = tid; idx < 2560; idx += 512) W6s[idx] = W6[idx];
    __syncthreads();
    // ---- stable descending rank (= jnp.argsort(-key) first 64) ----
    if (tid < 128) {
        float myk = key[tid];
        int r = 0;
        for (int j = 0; j < 128; ++j) {
            float kj = key[j];
            r += (kj > myk) || (kj == myk && j < tid);
        }
        if (r < 64) ord[r] = (unsigned short)tid;
    }
    __syncthreads();

    // ---- z + relu + maxpool fused from Y ----
    {
        int c = tid & 15, pp = tid >> 4;                 // 512 = 16c x 32pp
        int n0 = ord[2 * pp] & 127, n1 = ord[2 * pp + 1] & 127;
        float b = b5[c];
        float z0 = fmaxf(b + Yl[n0 * 16 + c], 0.f);
        float z1 = fmaxf(b + Yl[n1 * 16 + c], 0.f);
        ZMP[c * 32 + pp] = fmaxf(z0, z1);
    }
    __syncthreads();
    // ---- conv1d(16,32,5) VALID + relu ----
    for (int oi = tid; oi < 896; oi += 512) {
        int oc = oi / 28, p = oi % 28;
        float s = b6[oc];
#pragma unroll
        for (int i = 0; i < 16; ++i) {
            const float* wrow = W6s + (oc * 16 + i) * 5;
#pragma unroll
            for (int k = 0; k < 5; ++k)
                s += ZMP[i * 32 + p + k] * wrow[k];
        }
        Z896[oi] = fmaxf(s, 0.f);
    }
    __syncthreads();
    // ---- fc1 (896->128), split-K x4 ----
    {
        int f = tid & 127, q = tid >> 7;                 // q in [0,4)
        float s = 0.f;
        for (int i = q * 224; i < (q + 1) * 224; ++i)
            s += Z896[i] * Wf1[i * 128 + f];
        PART[q * 128 + f] = s;
    }
    __syncthreads();
    if (tid < 128) {
        float s = bf1[tid];
#pragma unroll
        for (int q = 0; q < 4; ++q) s += PART[q * 128 + tid];
        FC1[tid] = fmaxf(s, 0.f);
    }
    __syncthreads();
    // ---- fc2 (128->10) + log_softmax ----
    if (tid < 10) {
        float s = bf2[tid];
        for (int i = 0; i < 128; ++i) s += FC1[i] * Wf2[i * 10 + tid];
        LG[tid] = s;
    }
    __syncthreads();
    if (tid == 0) {
        float mx = LG[0];
        for (int i = 1; i < 10; ++i) mx = fmaxf(mx, LG[i]);
        float se = 0.f;
        for (int i = 0; i < 10; ++i) se += expf(LG[i] - mx);
        LG[16] = mx + logf(se);
    }
    __syncthreads();
    if (tid < 10)
        out[g * 10 + tid] = LG[tid] - LG[16];
}

extern "C" void kernel_launch(void* const* d_in, const int* in_sizes, int n_in,
                              void* d_out, int out_size, void* d_ws, size_t ws_size,
                              hipStream_t stream) {
    (void)in_sizes; (void)n_in; (void)out_size; (void)ws_size;
    const float* x   = (const float*)d_in[0];
    const float* W1  = (const float*)d_in[1];
    const float* b1  = (const float*)d_in[2];
    const float* W2  = (const float*)d_in[3];
    const float* b2  = (const float*)d_in[4];
    const float* W3  = (const float*)d_in[5];
    const float* b3  = (const float*)d_in[6];
    const float* W4  = (const float*)d_in[7];
    const float* b4  = (const float*)d_in[8];
    const float* W5  = (const float*)d_in[9];
    const float* b5  = (const float*)d_in[10];
    const float* W6  = (const float*)d_in[11];
    const float* b6  = (const float*)d_in[12];
    const float* Wf1 = (const float*)d_in[13];
    const float* bf1 = (const float*)d_in[14];
    const float* Wf2 = (const float*)d_in[15];
    const float* bf2 = (const float*)d_in[16];
    const int* ei  = (const int*)d_in[17];
    const int* src = ei;
    const int* dst = ei + N_EDGES;

    char* ws = (char*)d_ws;
    unsigned short* ebuf = (unsigned short*)(ws);             // u16[512*2048] = 2 MB
    unsigned*       cstab = (unsigned*)(ws + 2097152);        // u32[512*512] = 1 MB

    scatter_kernel<<<SBLK, 256, 0, stream>>>(src, dst, cstab, ebuf);
    mega_kernel<<<N_GRAPH, 512, 0, stream>>>(x, W1, b1, W2, b2, W3, b3, W4, b4,
                                             W5, b5, W6, b6, Wf1, bf1, Wf2, bf2,
                                             cstab, ebuf, (float*)d_out);
}

// Round 20
// 254.577 us; speedup vs baseline: 1.0612x; 1.0612x over previous
//
#include <hip/hip_runtime.h>

#define N_EDGES 1048576
#define N_GRAPH 512
#define MAXE    2304
#define CHUNK   2048
#define SBLK    (N_EDGES / CHUNK)   // 512

typedef __attribute__((ext_vector_type(4))) float floatx4;
typedef __attribute__((ext_vector_type(4))) int intx4;

// ---------------- preprocessing: fully local counting sort ----------------
__global__ void scatter_kernel(const int* __restrict__ src, const int* __restrict__ dst,
                               unsigned* __restrict__ cstab, unsigned short* __restrict__ ebuf) {
    __shared__ unsigned short sbuf[CHUNK];
    __shared__ unsigned short sg[CHUNK];
    __shared__ unsigned lhist[512];
    __shared__ unsigned lscan[512];
    const int t = threadIdx.x;
    const int b = blockIdx.x;
    lhist[t] = 0; lhist[t + 256] = 0;
    __syncthreads();
    const intx4* s4 = (const intx4*)(src + b * CHUNK) + t * 2;
    const intx4* d4 = (const intx4*)(dst + b * CHUNK) + t * 2;
    unsigned short gg[8], pk[8], rr[8];
#pragma unroll
    for (int h = 0; h < 2; ++h) {
        intx4 sv = s4[h], dv = d4[h];
        int ss[4] = {sv.x, sv.y, sv.z, sv.w};
        int dd[4] = {dv.x, dv.y, dv.z, dv.w};
#pragma unroll
        for (int j = 0; j < 4; ++j) {
            unsigned g = ((unsigned)dd[j]) >> 7;
            gg[h * 4 + j] = (unsigned short)g;
            pk[h * 4 + j] = (unsigned short)((ss[j] & 127) | ((dd[j] & 127) << 8));
            rr[h * 4 + j] = (unsigned short)atomicAdd(&lhist[g], 1u);
        }
    }
    __syncthreads();
    unsigned a0 = lhist[t], a1 = lhist[t + 256];
    lscan[t] = a0; lscan[t + 256] = a1;
    __syncthreads();
    for (int d = 1; d < 512; d <<= 1) {
        unsigned v0 = (t >= d) ? lscan[t - d] : 0u;
        unsigned v1 = (t + 256 >= d) ? lscan[t + 256 - d] : 0u;
        __syncthreads();
        lscan[t] += v0; lscan[t + 256] += v1;
        __syncthreads();
    }
    lscan[t] -= a0; lscan[t + 256] -= a1;
    cstab[(size_t)t * SBLK + b]         = (a0 << 16) | lscan[t];
    cstab[(size_t)(t + 256) * SBLK + b] = (a1 << 16) | lscan[t + 256];
    __syncthreads();
#pragma unroll
    for (int j = 0; j < 8; ++j) {
        unsigned pos = lscan[gg[j]] + rr[j];
        sbuf[pos] = pk[j]; sg[pos] = gg[j];
    }
    __syncthreads();
    for (int i = t; i < CHUNK; i += 256)
        ebuf[(size_t)b * CHUNK + i] = sbuf[i];
    (void)sg;
}

// ---------------- GCN layer, 512 threads (in-place X, split csr/coef) -----
template<int CIN, int COUT>
__device__ void gcn_layer(const float* Xin, float* Xio,
                          const float* __restrict__ W, const float* __restrict__ Bv,
                          const float* __restrict__ dinv, const int* __restrict__ offs,
                          const unsigned char* __restrict__ csr,
                          const float* __restrict__ coef, int tid)
{
    constexpr int CL  = COUT / 4;
    constexpr int GR  = 512 / CL;
    constexpr int NPT = 128 / GR;        // 8 / 4 / 2
    const int grp = tid / CL, cl = tid % CL;

    float acc[NPT][4];
#pragma unroll
    for (int ni = 0; ni < NPT; ++ni)
#pragma unroll
        for (int j = 0; j < 4; ++j) acc[ni][j] = 0.f;

#pragma unroll 1                      // keep k-loop rolled: caps wv/xv live ranges
    for (int k = 0; k < CIN; k += 4) {
        float wv[4][4];
#pragma unroll
        for (int i = 0; i < 4; ++i)
            *(floatx4*)wv[i] = *(const floatx4*)(W + (k + i) * COUT + cl * 4);
#pragma unroll
        for (int ni = 0; ni < NPT; ++ni) {
            floatx4 xv = *(const floatx4*)(Xin + (grp * NPT + ni) * CIN + k);
#pragma unroll
            for (int i = 0; i < 4; ++i)
#pragma unroll
                for (int j = 0; j < 4; ++j)
                    acc[ni][j] += xv[i] * wv[i][j];
        }
    }
    __syncthreads();                 // ALL Xin reads done (in-place safe)
#pragma unroll
    for (int ni = 0; ni < NPT; ++ni) {
        floatx4 v; v[0] = acc[ni][0]; v[1] = acc[ni][1]; v[2] = acc[ni][2]; v[3] = acc[ni][3];
        *(floatx4*)(Xio + (grp * NPT + ni) * COUT + cl * 4) = v;
    }
    __syncthreads();                 // H visible

    floatx4 bv = *(const floatx4*)(Bv + cl * 4);
#pragma unroll
    for (int ni = 0; ni < NPT; ++ni) {
        int n = grp * NPT + ni;
        float a[4] = {0.f, 0.f, 0.f, 0.f};
        int o0 = offs[n], o1 = offs[n + 1];
        int p = o0;
        // 4-way software pipeline: batch index/coef loads, then 4 independent
        // b128 H loads -> 4x the MLP on the dependent LDS chain.
        for (; p + 3 < o1; p += 4) {
            int s0 = csr[p], s1 = csr[p + 1], s2 = csr[p + 2], s3 = csr[p + 3];
            float c0 = coef[p], c1 = coef[p + 1], c2 = coef[p + 2], c3 = coef[p + 3];
            floatx4 h0 = *(const floatx4*)(Xio + s0 * COUT + cl * 4);
            floatx4 h1 = *(const floatx4*)(Xio + s1 * COUT + cl * 4);
            floatx4 h2 = *(const floatx4*)(Xio + s2 * COUT + cl * 4);
            floatx4 h3 = *(const floatx4*)(Xio + s3 * COUT + cl * 4);
#pragma unroll
            for (int j = 0; j < 4; ++j)
                a[j] += (h0[j] * c0 + h1[j] * c1) + (h2[j] * c2 + h3[j] * c3);
        }
        for (; p < o1; ++p) {
            int s = csr[p];
            float cf = coef[p];
            floatx4 h = *(const floatx4*)(Xio + s * COUT + cl * 4);
#pragma unroll
            for (int j = 0; j < 4; ++j) a[j] += h[j] * cf;
        }
        float dn = dinv[n], dnn = dn * dn;
#pragma unroll
        for (int j = 0; j < 4; ++j)
            acc[ni][j] = tanhf(a[j] + acc[ni][j] * dnn + bv[j]);   // reuse acc
    }
    __syncthreads();                 // all H reads done before overwrite
#pragma unroll
    for (int ni = 0; ni < NPT; ++ni) {
        floatx4 v; v[0] = acc[ni][0]; v[1] = acc[ni][1]; v[2] = acc[ni][2]; v[3] = acc[ni][3];
        *(floatx4*)(Xio + (grp * NPT + ni) * COUT + cl * 4) = v;
    }
    __syncthreads();
}

// ---------------- Y accumulation, 512 threads, 4 registers/thread --------
template<int LEN, int OFF>
__device__ void yacc(const float* __restrict__ Xl, const float* __restrict__ W5,
                     int tid, float* __restrict__ Y)
{
    const int w = tid >> 6, lane = tid & 63, c = lane & 15, seg = lane >> 4;
    const float* wr = W5 + c * 256 + OFF + seg * 4;
#pragma unroll
    for (int half = 0; half < 2; ++half) {
        const float* xr = Xl + (w * 16 + half * 8) * LEN + seg * 4;
        float part[8];
#pragma unroll
        for (int r = 0; r < 8; ++r) part[r] = 0.f;
#pragma unroll 2                      // cap in-flight xv loads (spill control)
        for (int t = 0; t < LEN / 16; ++t) {
            floatx4 wv = *(const floatx4*)(wr + 16 * t);
#pragma unroll
            for (int r = 0; r < 8; ++r) {
                floatx4 xv = *(const floatx4*)(xr + r * LEN + 16 * t);
                part[r] += xv[0] * wv[0] + xv[1] * wv[1] + xv[2] * wv[2] + xv[3] * wv[3];
            }
        }
#pragma unroll
        for (int r = 0; r < 8; ++r) {
            float s = part[r];
            s += __shfl_xor(s, 16, 64);
            s += __shfl_xor(s, 32, 64);
            int rg = half * 8 + r;
            if (seg == (rg & 3)) Y[rg >> 2] += s;
        }
    }
}

// ---------------- fused per-graph kernel: 512 threads (R14/R18 config) ----
__global__ __launch_bounds__(512, 4) void mega_kernel(
    const float* __restrict__ x,
    const float* __restrict__ W1, const float* __restrict__ b1,
    const float* __restrict__ W2, const float* __restrict__ b2,
    const float* __restrict__ W3, const float* __restrict__ b3,
    const float* __restrict__ W4, const float* __restrict__ b4,
    const float* __restrict__ W5, const float* __restrict__ b5,
    const float* __restrict__ W6, const float* __restrict__ b6,
    const float* __restrict__ Wf1, const float* __restrict__ bf1,
    const float* __restrict__ Wf2, const float* __restrict__ bf2,
    const unsigned* __restrict__ cstab, const unsigned short* __restrict__ ebuf,
    float* __restrict__ out)
{
    __shared__ __align__(16) char pool[79248];
    int*   offs = (int*)(pool + 0);                       // int[129]
    float* dinv = (float*)(pool + 520);                   // f32[128]
    float* key  = (float*)(pool + 1032);                  // f32[128]
    unsigned short* ord = (unsigned short*)(pool + 1544); // u16[64]
    int*   ldeg = (int*)(pool + 1672);                    // int[128]
    unsigned char* csr = (unsigned char*)(pool + 2184);   // u8[2304]
    float* coef = (float*)(pool + 4488);                  // f32[2304]
    float* X    = (float*)(pool + 13712);                 // f32[16384] = 64 KB
    // tail overlays inside X (X dead after key + Y handoff):
    float* Yl   = X;                  // 128x16 = 2048 f
    float* ZMP  = X + 2048;           // 16x32  = 512 f
    float* W6s  = X + 3072;           // 2560 f
    float* Z896 = X + 5632;           // 896 f
    float* PART = X + 6528;           // 4x128 = 512 f
    float* FC1  = X + 7552;           // 128 f
    float* LG   = X + 7680;           // 17 f

    const int g   = blockIdx.x;
    const int tid = threadIdx.x;

    // ---- this thread's (block-bucket) run: streamed from global twice ----
    unsigned cs = cstab[(size_t)g * SBLK + tid];
    int start = (int)(cs & 0xFFFFu);
    int myc = (int)(cs >> 16);
    if (myc > 64) myc = 64;                 // safety bound only
    const unsigned short* run = ebuf + (size_t)tid * CHUNK + start;

    // ---- stage x into X EARLY: global loads complete under CSR phase ----
    const float* xg = x + (size_t)g * 16384;
    for (int idx = tid; idx < 4096; idx += 512)
        *(floatx4*)(X + idx * 4) = *(const floatx4*)(xg + idx * 4);

    // ---- degree histogram (pass 1 over run) ----
    if (tid < 128) ldeg[tid] = 0;
    __syncthreads();
    for (int w = 0; w < myc; ++w)
        atomicAdd(&ldeg[(run[w] >> 8) & 127], 1);
    __syncthreads();
    // ---- single-wave shfl scan over 128 degree counts ----
    if (tid < 64) {
        int v0 = ldeg[2 * tid], v1 = ldeg[2 * tid + 1];
        int s = v0 + v1;
        for (int d = 1; d < 64; d <<= 1) {
            int u = __shfl_up(s, d, 64);
            if (tid >= d) s += u;
        }
        int e1 = s - v1, e2 = s;
        offs[2 * tid + 1] = (e1 < MAXE) ? e1 : MAXE;
        offs[2 * tid + 2] = (e2 < MAXE) ? e2 : MAXE;
        if (tid == 0) offs[0] = 0;
    }
    if (tid >= 128 && tid < 256) {
        int n = tid - 128;
        dinv[n] = 1.0f / sqrtf((float)(1 + ldeg[n]));
    }
    __syncthreads();
    if (tid < 128) ldeg[tid] = offs[tid];               // cursor
    __syncthreads();
    // ---- scatter into csr (u8) + coef (f32) (pass 2 over run, L2-hot) ----
    for (int w = 0; w < myc; ++w) {
        unsigned e = run[w];
        int dn_ = (e >> 8) & 127, sn = e & 127;
        int p = atomicAdd(&ldeg[dn_], 1);
        if (p < MAXE) {
            csr[p]  = (unsigned char)sn;
            coef[p] = dinv[sn] * dinv[dn_];
        }
    }
    __syncthreads();   // covers CSR scatter AND the early x staging

    // ---- 4 GCN layers, all in-place in X, + register-Y accumulation ----
    float Y[4] = {0.f, 0.f, 0.f, 0.f};
    gcn_layer<128, 128>(X, X, W1, b1, dinv, offs, csr, coef, tid);
    yacc<128,   0>(X, W5, tid, Y);
    gcn_layer<128,  64>(X, X, W2, b2, dinv, offs, csr, coef, tid);
    yacc< 64, 128>(X, W5, tid, Y);
    gcn_layer< 64,  32>(X, X, W3, b3, dinv, offs, csr, coef, tid);
    yacc< 32, 192>(X, W5, tid, Y);
    gcn_layer< 32,  32>(X, X, W4, b4, dinv, offs, csr, coef, tid);
    yacc< 32, 224>(X, W5, tid, Y);

    // ---- key extraction (before X reuse), then Y -> LDS ----
    if (tid < 128) key[tid] = X[tid * 32 + 31];
    __syncthreads();
    {
        const int w = tid >> 6, lane = tid & 63, c = lane & 15, seg = lane >> 4;
#pragma unroll
        for (int q = 0; q < 4; ++q)
            Yl[(w * 16 + seg + 4 * q) * 16 + c] = Y[q];
    }
    if (tid < 64) ord[tid] = (unsigned short)tid;       // safety default
    for (int idx = tid; idx < 2560; idx += 512) W6s[idx] = W6[idx];
    __syncthreads();
    // ---- stable descending rank (= jnp.argsort(-key) first 64) ----
    if (tid < 128) {
        float myk = key[tid];
        int r = 0;
        for (int j = 0; j < 128; ++j) {
            float kj = key[j];
            r += (kj > myk) || (kj == myk && j < tid);
        }
        if (r < 64) ord[r] = (unsigned short)tid;
    }
    __syncthreads();

    // ---- z + relu + maxpool fused from Y ----
    {
        int c = tid & 15, pp = tid >> 4;                 // 512 = 16c x 32pp
        int n0 = ord[2 * pp] & 127, n1 = ord[2 * pp + 1] & 127;
        float b = b5[c];
        float z0 = fmaxf(b + Yl[n0 * 16 + c], 0.f);
        float z1 = fmaxf(b + Yl[n1 * 16 + c], 0.f);
        ZMP[c * 32 + pp] = fmaxf(z0, z1);
    }
    __syncthreads();
    // ---- conv1d(16,32,5) VALID + relu ----
    for (int oi = tid; oi < 896; oi += 512) {
        int oc = oi / 28, p = oi % 28;
        float s = b6[oc];
#pragma unroll
        for (int i = 0; i < 16; ++i) {
            const float* wrow = W6s + (oc * 16 + i) * 5;
#pragma unroll
            for (int k = 0; k < 5; ++k)
                s += ZMP[i * 32 + p + k] * wrow[k];
        }
        Z896[oi] = fmaxf(s, 0.f);
    }
    __syncthreads();
    // ---- fc1 (896->128), split-K x4 ----
    {
        int f = tid & 127, q = tid >> 7;                 // q in [0,4)
        float s = 0.f;
        for (int i = q * 224; i < (q + 1) * 224; ++i)
            s += Z896[i] * Wf1[i * 128 + f];
        PART[q * 128 + f] = s;
    }
    __syncthreads();
    if (tid < 128) {
        float s = bf1[tid];
#pragma unroll
        for (int q = 0; q < 4; ++q) s += PART[q * 128 + tid];
        FC1[tid] = fmaxf(s, 0.f);
    }
    __syncthreads();
    // ---- fc2 (128->10) + log_softmax ----
    if (tid < 10) {
        float s = bf2[tid];
        for (int i = 0; i < 128; ++i) s += FC1[i] * Wf2[i * 10 + tid];
        LG[tid] = s;
    }
    __syncthreads();
    if (tid == 0) {
        float mx = LG[0];
        for (int i = 1; i < 10; ++i) mx = fmaxf(mx, LG[i]);
        float se = 0.f;
        for (int i = 0; i < 10; ++i) se += expf(LG[i] - mx);
        LG[16] = mx + logf(se);
    }
    __syncthreads();
    if (tid < 10)
        out[g * 10 + tid] = LG[tid] - LG[16];
}

extern "C" void kernel_launch(void* const* d_in, const int* in_sizes, int n_in,
                              void* d_out, int out_size, void* d_ws, size_t ws_size,
                              hipStream_t stream) {
    (void)in_sizes; (void)n_in; (void)out_size; (void)ws_size;
    const float* x   = (const float*)d_in[0];
    const float* W1  = (const float*)d_in[1];
    const float* b1  = (const float*)d_in[2];
    const float* W2  = (const float*)d_in[3];
    const float* b2  = (const float*)d_in[4];
    const float* W3  = (const float*)d_in[5];
    const float* b3  = (const float*)d_in[6];
    const float* W4  = (const float*)d_in[7];
    const float* b4  = (const float*)d_in[8];
    const float* W5  = (const float*)d_in[9];
    const float* b5  = (const float*)d_in[10];
    const float* W6  = (const float*)d_in[11];
    const float* b6  = (const float*)d_in[12];
    const float* Wf1 = (const float*)d_in[13];
    const float* bf1 = (const float*)d_in[14];
    const float* Wf2 = (const float*)d_in[15];
    const float* bf2 = (const float*)d_in[16];
    const int* ei  = (const int*)d_in[17];
    const int* src = ei;
    const int* dst = ei + N_EDGES;

    char* ws = (char*)d_ws;
    unsigned short* ebuf = (unsigned short*)(ws);             // u16[512*2048] = 2 MB
    unsigned*       cstab = (unsigned*)(ws + 2097152);        // u32[512*512] = 1 MB

    scatter_kernel<<<SBLK, 256, 0, stream>>>(src, dst, cstab, ebuf);
    mega_kernel<<<N_GRAPH, 512, 0, stream>>>(x, W1, b1, W2, b2, W3, b3, W4, b4,
                                             W5, b5, W6, b6, Wf1, bf1, Wf2, bf2,
                                             cstab, ebuf, (float*)d_out);
}